// Round 7
// baseline (1360.283 us; speedup 1.0000x reference)
//
#include <hip/hip_runtime.h>
#include <hip/hip_bf16.h>
#include <cstdint>

typedef __bf16 bf16_t;
typedef __bf16 bf16x8 __attribute__((ext_vector_type(8)));
typedef float f32x4 __attribute__((ext_vector_type(4)));

#define BB 8
#define TT 2048
#define TC 512             // outer chunk length (4 chunks)
#define TCLOG 9
#define NCHUNK 4
#define MCH (BB*TC)        // 4096 local rows per chunk
#define CCH 1024
#define HH 16
#define HSZ 64
#define LR5 160            // 5 * LORA_R
#define LRP 192            // lora width padded to BKK multiple (cols 160..191 are zero)
#define TDR 64
#define TDK 128            // doubled K for hi/lo split w-GEMM
#define TSUB 64            // scan sub-chunk length
#define NSC (TC/TSUB)      // 8 sub-chunks per outer chunk
#define BBHH (BB*HH)       // 128
#define LDP 72             // LDS tile pitch for wkv tiles (64 + 8)

#define BM 128
#define BN 128
#define BKK 32             // 32KB dbuf LDS -> 4-5 blocks/CU residency (R6 lesson)

enum { EPI_NONE = 0, EPI_SILU = 1, EPI_TANH = 2, EPI_XX = 3, EPI_WBIAS = 4 };

// ---------------- async global->LDS, 16B per lane (m97 recipe) ----------------
__device__ __forceinline__ void gload16(const bf16_t* g, bf16_t* l) {
    __builtin_amdgcn_global_load_lds(
        (__attribute__((address_space(1))) void*)(g),
        (__attribute__((address_space(3))) void*)(l), 16, 0, 0);
}

// ---------------- f32 -> bf16 convert ----------------
__global__ __launch_bounds__(256) void f2b_kernel(const float* __restrict__ in,
        bf16_t* __restrict__ out, int n) {
    int i = blockIdx.x * 256 + threadIdx.x;
    if (i < n) out[i] = (bf16_t)in[i];
}

// ---------------- padded transpose+convert: in (R,Cc) f32 -> out (Cp,R) bf16, rows>=Cc zero ----------------
__global__ __launch_bounds__(256) void transb_pad(const float* __restrict__ in,
        bf16_t* __restrict__ out, int R, int Cc, int Cp) {
    int i = blockIdx.x * 256 + threadIdx.x;     // over Cp*R
    if (i >= Cp * R) return;
    int row = i / R, col = i - row * R;          // out[row][col]
    out[i] = (row < Cc) ? (bf16_t)in[(size_t)col * Cc + row] : (bf16_t)0.f;
}

// ---------------- block-diagonal B_lora -> Bbig [5120][192] bf16 (zeros included) ----------------
__global__ __launch_bounds__(256) void bbig_pad(const float* __restrict__ B_lora,
        bf16_t* __restrict__ Bbig) {
    int i = blockIdx.x * 256 + threadIdx.x;     // over 5*CCH*LRP
    if (i >= 5 * CCH * LRP) return;
    int row = i / LRP, col = i - row * LRP;
    int f = row >> 10, c = row & (CCH - 1);
    int lo = f * 32;
    float v = 0.f;
    if (col >= lo && col < lo + 32)
        v = B_lora[(size_t)(lo + (col - lo)) * CCH + c];
    Bbig[i] = (bf16_t)v;
}

// ---------------- td_B hi/lo split, transposed: (64,1024) f32 -> (1024,128) bf16 ----------------
__global__ __launch_bounds__(256) void tdb2_kernel(const float* __restrict__ td_B,
        bf16_t* __restrict__ tdB2) {
    int i = blockIdx.x * 256 + threadIdx.x;     // over CCH*TDR
    if (i >= CCH * TDR) return;
    int n = i >> 6, k = i & 63;
    float f = td_B[(size_t)k * CCH + n];
    bf16_t hi = (bf16_t)f;
    bf16_t lo = (bf16_t)(f - (float)hi);
    tdB2[(size_t)n * TDK + k] = hi;
    tdB2[(size_t)n * TDK + TDR + k] = lo;
}

// ---------------- xm + bf16 x / dxa chunk buffers (f32 in, bf16 out x3) ----------------
__global__ __launch_bounds__(256) void xm_kernel(const float* __restrict__ x,
        const float* __restrict__ miu_x, bf16_t* __restrict__ xm,
        bf16_t* __restrict__ xb, bf16_t* __restrict__ dxb, int cOff) {
    long long i = (long long)blockIdx.x * 256 + threadIdx.x;   // over MCH*CCH
    int ch = (int)(i & (CCH - 1));
    int btl = (int)(i >> 10);                 // local row in [0, MCH)
    int b = btl >> TCLOG, tau = btl & (TC - 1);
    int t = cOff + tau;
    size_t gi = ((size_t)b * TT + t) * CCH + ch;
    float xv = x[gi];
    float xp = (t > 0) ? x[gi - CCH] : 0.f;
    float dx = xp - xv;
    xm[i]  = (bf16_t)(xv + dx * miu_x[ch]);
    xb[i]  = (bf16_t)xv;
    dxb[i] = (bf16_t)dx;
}

// ---------------- job-batched MFMA GEMM: out[m,n] = sum_k A[m,k]*Bw[n,k] ----------------
// BKK=32 double-buffer (32KB LDS total -> 4-5 blocks/CU; R6: 64KB capped us at 2)
// + counted vmcnt(4) pipeline (next tile's 4 loads fly across the barrier)
// + T2-lite XOR swizzle: 64B rows have only 4 b128 slots -> best spread is
//   4-way residual conflict (1.58x, m136) vs 8-way unswizzled.
// Barrier 1: own old-4 done (vmcnt) for every wave => buf[cur] valid.
// Barrier 2: all reads done before any wave ISSUES next writes.
struct GJob {
    const bf16_t* A;     // [M=4096][K]
    const bf16_t* Bw;    // [nbmax][K], rows >= N are ZERO (padded)
    void* C;
    int N;               // valid output cols
    int nbmax;           // allocated B rows (block skipped if n0 >= nbmax)
    int K;
    int ldc;
    int epi;
    int outf32;
    int cmap;            // map m -> global token rows (cOff)
    int dup;             // duplicate store at n+64 (bf16 path only)
};
struct GJobs { GJob j[5]; };

__global__ __launch_bounds__(256) void gemm_jobs(GJobs jobs,
        const float* __restrict__ lam, const float* __restrict__ tdmiu,
        const bf16_t* __restrict__ xb, const bf16_t* __restrict__ dxb,
        bf16_t* __restrict__ xx5, int cOff) {
    const GJob jb = jobs.j[blockIdx.z];
    const int m0 = blockIdx.x * BM;
    const int n0 = blockIdx.y * BN;
    if (n0 >= jb.nbmax) return;              // block-uniform: no barrier divergence
    const int K = jb.K;
    __shared__ __align__(16) bf16_t As[2][BM * BKK];
    __shared__ __align__(16) bf16_t Bs[2][BN * BKK];
    const int tid = threadIdx.x;
    const int w = tid >> 6, lane = tid & 63;
    const int wm = (w >> 1) * 64, wn = (w & 1) * 64;  // 2x2 waves, 64x64 each
    const int lrow = lane & 15;
    const int kq = (lane >> 4) * 8;
    const int srow = tid >> 2;          // staging row base (0..63); row = srow + p*64
    // T2-lite source swizzle: chunk ^= row&3  ((row&3)==(srow&3), p*64%4==0 -> const)
    const int sc8 = (((tid & 3) ^ (srow & 3)) * 8);
    // T2-lite read swizzle: (row&3) == (lrow&3)  (wm, mt*16 % 4 == 0 -> const)
    const int rsw = (lrow & 3) << 3;
    const bf16_t* Ab = jb.A + (size_t)m0 * K;
    const bf16_t* Bb = jb.Bw + (size_t)n0 * K;
    f32x4 acc[4][4] = {};
    const int nsteps = K / BKK;

    auto stage = [&](int buf, int k0) {      // 4 vmem ops per thread
        #pragma unroll
        for (int p = 0; p < 2; ++p) {
            int r = srow + p * 64;
            // LDS dest (tid + p*256)*16B = wave-base + lane*16 (linear, m104-safe)
            gload16(Ab + (size_t)r * K + k0 + sc8, &As[buf][(tid + p * 256) * 8]);
            gload16(Bb + (size_t)r * K + k0 + sc8, &Bs[buf][(tid + p * 256) * 8]);
        }
    };

    stage(0, 0);
    int cur = 0;
    for (int s = 0; s < nsteps; ++s) {
        if (s + 1 < nsteps) {
            stage(cur ^ 1, (s + 1) * BKK);   // issue next tile: flies through barrier
            asm volatile("s_waitcnt vmcnt(4)" ::: "memory");   // old 4 (cur tile) done
        } else {
            asm volatile("s_waitcnt vmcnt(0)" ::: "memory");   // epilogue drain
        }
        __builtin_amdgcn_sched_barrier(0);
        __builtin_amdgcn_s_barrier();        // all waves' cur-tile loads landed
        __builtin_amdgcn_sched_barrier(0);
        __builtin_amdgcn_s_setprio(1);
        {
            bf16x8 af[4], bfr[4];
            #pragma unroll
            for (int mt = 0; mt < 4; ++mt)
                af[mt] = *(const bf16x8*)(&As[cur][(wm + mt * 16 + lrow) * BKK + (kq ^ rsw)]);
            #pragma unroll
            for (int nt = 0; nt < 4; ++nt)
                bfr[nt] = *(const bf16x8*)(&Bs[cur][(wn + nt * 16 + lrow) * BKK + (kq ^ rsw)]);
            #pragma unroll
            for (int mt = 0; mt < 4; ++mt)
                #pragma unroll
                for (int nt = 0; nt < 4; ++nt)
                    acc[mt][nt] = __builtin_amdgcn_mfma_f32_16x16x32_bf16(
                        af[mt], bfr[nt], acc[mt][nt], 0, 0, 0);
        }
        __builtin_amdgcn_s_setprio(0);
        __builtin_amdgcn_sched_barrier(0);
        __builtin_amdgcn_s_barrier();        // reads done before next writes ISSUE
        cur ^= 1;
    }
    // C/D layout: col = lane&15, row = (lane>>4)*4 + reg  [verified m89/m91]
    const int rbase = (lane >> 4) * 4;
    const int col = lane & 15;
    if (jb.epi == EPI_XX) {
        #pragma unroll
        for (int mt = 0; mt < 4; ++mt)
            #pragma unroll
            for (int nt = 0; nt < 4; ++nt) {
                int n = n0 + wn + nt * 16 + col;
                int f = n >> 10, cch = n & (CCH - 1);
                #pragma unroll
                for (int rg = 0; rg < 4; ++rg) {
                    int m = m0 + wm + mt * 16 + rbase + rg;
                    size_t li = (size_t)m * CCH + cch;
                    float xv = (float)xb[li];
                    float dx = (float)dxb[li];
                    float miu = lam[f * CCH + cch] + acc[mt][nt][rg];
                    xx5[(size_t)(f * MCH + m) * CCH + cch] = (bf16_t)(xv + dx * miu);
                }
            }
        return;
    }
    #pragma unroll
    for (int mt = 0; mt < 4; ++mt) {
        #pragma unroll
        for (int nt = 0; nt < 4; ++nt) {
            int n = n0 + wn + nt * 16 + col;
            if (n >= jb.N) continue;
            #pragma unroll
            for (int rg = 0; rg < 4; ++rg) {
                int m = m0 + wm + mt * 16 + rbase + rg;
                size_t mg = jb.cmap ? ((size_t)(m >> TCLOG) * TT + cOff + (m & (TC - 1)))
                                    : (size_t)m;
                float vv = acc[mt][nt][rg];
                if (jb.epi == EPI_SILU) vv = vv / (1.f + expf(-vv));
                else if (jb.epi == EPI_TANH) vv = tanhf(vv);
                else if (jb.epi == EPI_WBIAS) vv += tdmiu[n];
                if (jb.outf32) {
                    ((float*)jb.C)[mg * jb.ldc + n] = vv;
                } else {
                    bf16_t hv = (bf16_t)vv;
                    ((bf16_t*)jb.C)[mg * jb.ldc + n] = hv;
                    if (jb.dup) ((bf16_t*)jb.C)[mg * jb.ldc + n + TDR] = hv;
                }
            }
        }
    }
}

// ---------------- WKV6 pass 1+2a fused: decay cumprods, operand tiles, Sloc GEMM ----------------
__global__ __launch_bounds__(64) void wkv_prepsg(const bf16_t* __restrict__ ry,
        const bf16_t* __restrict__ k, const float* __restrict__ w,
        const bf16_t* __restrict__ v, const float* __restrict__ u,
        bf16_t* __restrict__ rrT, bf16_t* __restrict__ ktT,
        float* __restrict__ PL, float* __restrict__ bvec,
        float* __restrict__ Sloc) {
    const int bh = blockIdx.x, sc = blockIdx.y;
    const int b = bh >> 4, h = bh & 15;
    const int j = threadIdx.x;
    const size_t base = ((size_t)b * TC + sc * TSUB) * CCH + h * HSZ + j;
    const size_t tile = ((size_t)bh * NSC + sc) * (TSUB * HSZ);
    const size_t vb = (size_t)bh * NSC + sc;
    __shared__ __align__(16) bf16_t ksT[HSZ * LDP];   // [i][s] = kt[s][i] (unscaled)
    __shared__ __align__(16) bf16_t vtT[HSZ * LDP];   // [n][s] = v[s][n]
    __shared__ float pls[HSZ];
    const float uj = u[h * HSZ + j];
    float pex = 1.f;
    for (int t = 0; t < TSUB; ++t) {
        size_t idx = base + (size_t)t * CCH;
        float rv = (float)ry[idx], kv = (float)k[idx], wv = w[idx];
        bf16_t vv = v[idx];
        float d = expf(-expf(wv));
        rrT[tile + t * HSZ + j] = (bf16_t)(rv * pex);
        float pinc = pex * d;
        bf16_t ktv = (bf16_t)(kv / pinc);   // |kt| <= ~3e11, bf16-safe
        ktT[tile + t * HSZ + j] = ktv;
        ksT[j * LDP + t] = ktv;
        vtT[j * LDP + t] = vv;
        float bu = rv * uj * kv;
        #pragma unroll
        for (int off = 1; off < 64; off <<= 1) bu += __shfl_xor(bu, off);
        if (j == 0) bvec[vb * TSUB + t] = bu;
        pex = pinc;
    }
    PL[vb * HSZ + j] = pex;
    pls[j] = pex;
    __syncthreads();
    // Sloc[i][n] = PL[i] * sum_s kt[s][i] * v[s][n]  (PL scale in f32 epilogue)
    const int lrow = j & 15, kq = (j >> 4) * 8;
    f32x4 acc[4][4] = {};
    #pragma unroll
    for (int kk = 0; kk < TSUB; kk += 32) {
        bf16x8 af[4], bfr[4];
        #pragma unroll
        for (int mt = 0; mt < 4; ++mt)
            af[mt] = *(const bf16x8*)(&ksT[(mt * 16 + lrow) * LDP + kk + kq]);
        #pragma unroll
        for (int nt = 0; nt < 4; ++nt)
            bfr[nt] = *(const bf16x8*)(&vtT[(nt * 16 + lrow) * LDP + kk + kq]);
        #pragma unroll
        for (int mt = 0; mt < 4; ++mt)
            #pragma unroll
            for (int nt = 0; nt < 4; ++nt)
                acc[mt][nt] = __builtin_amdgcn_mfma_f32_16x16x32_bf16(
                    af[mt], bfr[nt], acc[mt][nt], 0, 0, 0);
    }
    const int rbase = (j >> 4) * 4, col = j & 15;
    #pragma unroll
    for (int mt = 0; mt < 4; ++mt)
        #pragma unroll
        for (int nt = 0; nt < 4; ++nt)
            #pragma unroll
            for (int rg = 0; rg < 4; ++rg) {
                int i = mt * 16 + rbase + rg, n = nt * 16 + col;
                Sloc[tile + i * HSZ + n] = pls[i] * acc[mt][nt][rg];
            }
}

// ---------------- WKV6 pass 2b: serial state combine across sub-chunks ----------------
__global__ __launch_bounds__(64) void wkv_combine(const float* __restrict__ Sloc,
        const float* __restrict__ PL, float* __restrict__ S0st,
        float* state, int cOuter) {
    const int bh = blockIdx.x;
    const int j = threadIdx.x;
    float* st = state + (size_t)bh * HSZ * HSZ;
    float S[HSZ];
    if (cOuter > 0) {
        #pragma unroll
        for (int i = 0; i < HSZ; ++i) S[i] = st[i * HSZ + j];
    } else {
        #pragma unroll
        for (int i = 0; i < HSZ; ++i) S[i] = 0.f;
    }
    __shared__ float pls[HSZ];
    for (int sc = 0; sc < NSC; ++sc) {
        const size_t so = ((size_t)bh * NSC + sc) * (HSZ * HSZ);
        pls[j] = PL[((size_t)bh * NSC + sc) * HSZ + j];
        __syncthreads();
        #pragma unroll
        for (int i = 0; i < HSZ; ++i) {
            S0st[so + i * HSZ + j] = S[i];
            S[i] = pls[i] * S[i] + Sloc[so + i * HSZ + j];
        }
        __syncthreads();
    }
    #pragma unroll
    for (int i = 0; i < HSZ; ++i) st[i * HSZ + j] = S[i];
}

// ---------------- WKV6 pass 3: Y = (mask(RR@KTt) + diag(b)) @ V + RR @ S0 ----------------
__global__ __launch_bounds__(64) void wkv_y(bf16_t* __restrict__ ry,
        const bf16_t* __restrict__ rrT, const bf16_t* __restrict__ ktT,
        const bf16_t* __restrict__ v, const float* __restrict__ S0st,
        const float* __restrict__ bvec) {
    const int bh = blockIdx.x, sc = blockIdx.y;
    const int b = bh >> 4, h = bh & 15;
    const int j = threadIdx.x;
    const size_t tile = ((size_t)bh * NSC + sc) * (TSUB * HSZ);
    const size_t basev = ((size_t)b * TC + sc * TSUB) * CCH + h * HSZ;
    __shared__ __align__(16) bf16_t vtT[HSZ * LDP];   // [j][s] = v[s][j]
    __shared__ __align__(16) bf16_t s0T[HSZ * LDP];   // [j][i] = S0[i][j]
    __shared__ __align__(16) bf16_t am[TSUB * LDP];   // masked A [t][s]
    __shared__ float bl[TSUB];
    for (int s = 0; s < TSUB; ++s)
        vtT[j * LDP + s] = v[basev + (size_t)s * CCH + j];
    for (int i = 0; i < HSZ; ++i)
        s0T[j * LDP + i] = (bf16_t)S0st[tile + i * HSZ + j];
    bl[j] = bvec[((size_t)bh * NSC + sc) * TSUB + j];
    __syncthreads();
    const bf16_t* rrt = rrT + tile;
    const bf16_t* ktt = ktT + tile;
    const int lane = j;
    const int lrow = lane & 15, kq = (lane >> 4) * 8;
    const int rbase = (lane >> 4) * 4, col = lane & 15;
    // phase 1: A = RR @ KTt^T  (K = channel)
    f32x4 acc[4][4] = {};
    #pragma unroll
    for (int kk = 0; kk < HSZ; kk += 32) {
        bf16x8 af[4], bfr[4];
        #pragma unroll
        for (int mt = 0; mt < 4; ++mt)
            af[mt] = *(const bf16x8*)(rrt + (mt * 16 + lrow) * HSZ + kk + kq);
        #pragma unroll
        for (int nt = 0; nt < 4; ++nt)
            bfr[nt] = *(const bf16x8*)(ktt + (nt * 16 + lrow) * HSZ + kk + kq);
        #pragma unroll
        for (int mt = 0; mt < 4; ++mt)
            #pragma unroll
            for (int nt = 0; nt < 4; ++nt)
                acc[mt][nt] = __builtin_amdgcn_mfma_f32_16x16x32_bf16(
                    af[mt], bfr[nt], acc[mt][nt], 0, 0, 0);
    }
    // mask strict-lower, diag = b_t, upper = 0
    #pragma unroll
    for (int mt = 0; mt < 4; ++mt)
        #pragma unroll
        for (int nt = 0; nt < 4; ++nt)
            #pragma unroll
            for (int rg = 0; rg < 4; ++rg) {
                int t = mt * 16 + rbase + rg, s = nt * 16 + col;
                float aval = (s < t) ? acc[mt][nt][rg] : ((s == t) ? bl[t] : 0.f);
                am[t * LDP + s] = (bf16_t)aval;
            }
    __syncthreads();
    // phase 2: Y = A @ V  (K = s)  +  RR @ S0 (K = i)
    f32x4 yac[4][4] = {};
    #pragma unroll
    for (int kk = 0; kk < TSUB; kk += 32) {
        bf16x8 af[4], bfr[4];
        #pragma unroll
        for (int mt = 0; mt < 4; ++mt)
            af[mt] = *(const bf16x8*)(&am[(mt * 16 + lrow) * LDP + kk + kq]);
        #pragma unroll
        for (int nt = 0; nt < 4; ++nt)
            bfr[nt] = *(const bf16x8*)(&vtT[(nt * 16 + lrow) * LDP + kk + kq]);
        #pragma unroll
        for (int mt = 0; mt < 4; ++mt)
            #pragma unroll
            for (int nt = 0; nt < 4; ++nt)
                yac[mt][nt] = __builtin_amdgcn_mfma_f32_16x16x32_bf16(
                    af[mt], bfr[nt], yac[mt][nt], 0, 0, 0);
    }
    #pragma unroll
    for (int kk = 0; kk < HSZ; kk += 32) {
        bf16x8 af[4], bfr[4];
        #pragma unroll
        for (int mt = 0; mt < 4; ++mt)
            af[mt] = *(const bf16x8*)(rrt + (mt * 16 + lrow) * HSZ + kk + kq);
        #pragma unroll
        for (int nt = 0; nt < 4; ++nt)
            bfr[nt] = *(const bf16x8*)(&s0T[(nt * 16 + lrow) * LDP + kk + kq]);
        #pragma unroll
        for (int mt = 0; mt < 4; ++mt)
            #pragma unroll
            for (int nt = 0; nt < 4; ++nt)
                yac[mt][nt] = __builtin_amdgcn_mfma_f32_16x16x32_bf16(
                    af[mt], bfr[nt], yac[mt][nt], 0, 0, 0);
    }
    #pragma unroll
    for (int mt = 0; mt < 4; ++mt)
        #pragma unroll
        for (int nt = 0; nt < 4; ++nt)
            #pragma unroll
            for (int rg = 0; rg < 4; ++rg) {
                int t = mt * 16 + rbase + rg, jc = nt * 16 + col;
                ry[basev + (size_t)t * CCH + jc] = (bf16_t)yac[mt][nt][rg];
            }
}

// ---------------- GroupNorm(16 groups of 64) * g, in-place on y chunk ----------------
__global__ __launch_bounds__(256) void gn_kernel(bf16_t* yg,
        const float* __restrict__ g_glob, const float* __restrict__ gamma,
        const float* __restrict__ beta, int cOff) {
    int wave = threadIdx.x >> 6, lane = threadIdx.x & 63;
    int gid = blockIdx.x * 4 + wave;          // over MCH*HH
    int h = gid & (HH - 1);
    int ml = gid >> 4;                        // local token row
    int b = ml >> TCLOG, tau = ml & (TC - 1);
    size_t lidx = (size_t)ml * CCH + h * HSZ + lane;
    size_t gidx = ((size_t)b * TT + cOff + tau) * CCH + h * HSZ + lane;
    float val = (float)yg[lidx];
    float s = val, s2 = val * val;
    #pragma unroll
    for (int off = 32; off > 0; off >>= 1) {
        s  += __shfl_xor(s, off);
        s2 += __shfl_xor(s2, off);
    }
    float mean = s * (1.f / HSZ);
    float var  = fmaxf(s2 * (1.f / HSZ) - mean * mean, 0.f);
    float inv  = rsqrtf(var + 1e-5f * HH);
    float yn = (val - mean) * inv * gamma[h * HSZ + lane] + beta[h * HSZ + lane];
    yg[lidx] = (bf16_t)(yn * g_glob[gidx]);
}

extern "C" void kernel_launch(void* const* d_in, const int* in_sizes, int n_in,
                              void* d_out, int out_size, void* d_ws, size_t ws_size,
                              hipStream_t stream) {
    const float* x       = (const float*)d_in[0];
    const float* miu_x   = (const float*)d_in[1];
    const float* lambda_ = (const float*)d_in[2];
    const float* A_lora  = (const float*)d_in[3];
    const float* B_lora  = (const float*)d_in[4];
    const float* td_miu  = (const float*)d_in[5];
    const float* td_A    = (const float*)d_in[6];
    const float* td_B    = (const float*)d_in[7];
    const float* u       = (const float*)d_in[8];
    const float* Wr      = (const float*)d_in[9];
    const float* Wk      = (const float*)d_in[10];
    const float* Wv      = (const float*)d_in[11];
    const float* Wg      = (const float*)d_in[12];
    const float* Wo      = (const float*)d_in[13];
    const float* gamma   = (const float*)d_in[14];
    const float* beta    = (const float*)d_in[15];
    float* out = (float*)d_out;

    // ---- workspace carve-up (~114 MiB) ----
    char* ws = (char*)d_ws;
    size_t off = 0;
    auto alloc = [&](size_t bytes) {
        char* p = ws + off;
        off += (bytes + 255) & ~(size_t)255;
        return (void*)p;
    };
    const size_t MCC = (size_t)MCH * CCH;               // 4M elems per chunk buffer
    // Aliasing plan (all lifetimes disjoint within the serial per-chunk schedule):
    //   xm  -> xx5+4MCC   (dead after lora GEMM)
    //   Sloc-> xx5[0..2)  S0st -> xx5[2..4)   (written after xx consumed)
    //   xb  -> kc,  dxb -> vc   (dead after EPI_XX; kc/vc written by projections after)
    bf16_t* xx5  = (bf16_t*)alloc(5 * MCC * 2);         // 40 MB
    float*  Sloc = (float*)xx5;                          // 16 MB over xx0,xx1
    float*  S0st = (float*)(xx5 + 2 * MCC);              // 16 MB over xx2,xx3
    bf16_t* xmb  = xx5 + 4 * MCC;                        //  8 MB over xx4
    bf16_t* kc   = (bf16_t*)alloc(MCC * 2);
    bf16_t* vc   = (bf16_t*)alloc(MCC * 2);
    bf16_t* xb16 = kc;                                   // bf16 x chunk (pre-projection)
    bf16_t* dx16 = vc;                                   // bf16 dxa chunk
    float*  wc   = (float*)alloc(MCC * 4);              // f32 w (fed to exp cumprod)
    bf16_t* ryc  = (bf16_t*)alloc(MCC * 2);             // r -> y -> yn*g
    bf16_t* rrT  = (bf16_t*)alloc(MCC * 2);
    bf16_t* ktT  = (bf16_t*)alloc(MCC * 2);
    bf16_t* lhcp = (bf16_t*)alloc((size_t)MCH * LRP * 2);   // tanh lora hidden, padded
    bf16_t* tdh2 = (bf16_t*)alloc((size_t)MCH * TDK * 2);   // tanh td hidden, duplicated cols
    bf16_t* At   = (bf16_t*)alloc((size_t)256 * CCH * 2);   // lora A^T, rows 160.. zero
    bf16_t* tdAt = (bf16_t*)alloc((size_t)128 * CCH * 2);   // td A^T, rows 64.. zero
    bf16_t* tdB2 = (bf16_t*)alloc((size_t)CCH * TDK * 2);   // td_B^T hi|lo split
    bf16_t* Bbig = (bf16_t*)alloc((size_t)5 * CCH * LRP * 2); // block-diag B_lora
    bf16_t* Wb[5];
    for (int i = 0; i < 5; ++i) Wb[i] = (bf16_t*)alloc((size_t)CCH * CCH * 2);
    float*  state = (float*)alloc((size_t)BBHH * HSZ * HSZ * 4);
    float*  PL    = (float*)alloc((size_t)BBHH * NSC * HSZ * 4);
    float*  bvec  = (float*)alloc((size_t)BBHH * NSC * TSUB * 4);
    (void)ws_size; (void)in_sizes; (void)n_in; (void)out_size;
    bf16_t* Wrb = Wb[0]; bf16_t* Wkb = Wb[1]; bf16_t* Wvb = Wb[2];
    bf16_t* Wgb = Wb[3]; bf16_t* Wob = Wb[4];

    // ---- weight prep (kernels only; no runtime memset -> graph-capture safe) ----
    const int WN = CCH * CCH;
    f2b_kernel<<<(WN + 255) / 256, 256, 0, stream>>>(Wr, Wrb, WN);
    f2b_kernel<<<(WN + 255) / 256, 256, 0, stream>>>(Wk, Wkb, WN);
    f2b_kernel<<<(WN + 255) / 256, 256, 0, stream>>>(Wv, Wvb, WN);
    f2b_kernel<<<(WN + 255) / 256, 256, 0, stream>>>(Wg, Wgb, WN);
    f2b_kernel<<<(WN + 255) / 256, 256, 0, stream>>>(Wo, Wob, WN);
    transb_pad<<<(256 * CCH + 255) / 256, 256, 0, stream>>>(A_lora, At, CCH, LR5, 256);
    transb_pad<<<(128 * CCH + 255) / 256, 256, 0, stream>>>(td_A, tdAt, CCH, TDR, 128);
    tdb2_kernel<<<(CCH * TDR + 255) / 256, 256, 0, stream>>>(td_B, tdB2);
    bbig_pad<<<(5 * CCH * LRP + 255) / 256, 256, 0, stream>>>(B_lora, Bbig);

    for (int c = 0; c < NCHUNK; ++c) {
        const int cOff = c * TC;
        // xm + bf16 x/dxa chunk buffers (xb16/dx16 live until EPI_XX completes)
        xm_kernel<<<MCC / 256, 256, 0, stream>>>(x, miu_x, xmb, xb16, dx16, cOff);
        // lora hidden: lhcp = tanh(xm @ A_lora), cols 160..191 = tanh(0) = 0
        {
            GJobs J = {};
            J.j[0] = {xmb, At, lhcp, LRP, 256, CCH, LRP, EPI_TANH, 0, 0, 0};
            gemm_jobs<<<dim3(32, 2, 1), 256, 0, stream>>>(J, lambda_, td_miu, xb16, dx16, xx5, cOff);
        }
        // miu GEMM + ddlerp epilogue -> all 5 xx branch buffers
        {
            GJobs J = {};
            J.j[0] = {lhcp, Bbig, nullptr, 5 * CCH, 5 * CCH, LRP, 0, EPI_XX, 0, 0, 0};
            gemm_jobs<<<dim3(32, 40, 1), 256, 0, stream>>>(J, lambda_, td_miu, xb16, dx16, xx5, cOff);
        }
        // batched projections: k, v, r, g(silu->out f32), td hidden(tanh, dup cols)
        {
            GJobs J = {};
            J.j[0] = {xx5 + 1 * MCC, Wkb,  kc,   CCH, CCH, CCH, CCH, EPI_NONE, 0, 0, 0};
            J.j[1] = {xx5 + 2 * MCC, Wvb,  vc,   CCH, CCH, CCH, CCH, EPI_NONE, 0, 0, 0};
            J.j[2] = {xx5 + 3 * MCC, Wrb,  ryc,  CCH, CCH, CCH, CCH, EPI_NONE, 0, 0, 0};
            J.j[3] = {xx5 + 4 * MCC, Wgb,  out,  CCH, CCH, CCH, CCH, EPI_SILU, 1, 1, 0};
            J.j[4] = {xx5 + 0 * MCC, tdAt, tdh2, TDR, 128, CCH, TDK, EPI_TANH, 0, 0, 1};
            gemm_jobs<<<dim3(32, 8, 5), 256, 0, stream>>>(J, lambda_, td_miu, xb16, dx16, xx5, cOff);
        }
        // w = td_miu + tdh2 @ [hi|lo]^T  (MFMA, f32-grade via hi/lo split, f32 out)
        {
            GJobs J = {};
            J.j[0] = {tdh2, tdB2, wc, CCH, CCH, TDK, CCH, EPI_WBIAS, 1, 0, 0};
            gemm_jobs<<<dim3(32, 8, 1), 256, 0, stream>>>(J, lambda_, td_miu, xb16, dx16, xx5, cOff);
        }
        // scan: fused prep+state-GEMM (writes Sloc over dead xx0/xx1) -> combine -> Y
        wkv_prepsg<<<dim3(BBHH, NSC), 64, 0, stream>>>(ryc, kc, wc, vc, u,
                                                       rrT, ktT, PL, bvec, Sloc);
        wkv_combine<<<BBHH, 64, 0, stream>>>(Sloc, PL, S0st, state, c);
        wkv_y<<<dim3(BBHH, NSC), 64, 0, stream>>>(ryc, rrT, ktT, vc, S0st, bvec);
        // groupnorm * g, then Wo projection (f32 out, global rows)
        gn_kernel<<<(MCH * HH) / 4, 256, 0, stream>>>(ryc, out, gamma, beta, cOff);
        {
            GJobs J = {};
            J.j[0] = {ryc, Wob, out, CCH, CCH, CCH, CCH, EPI_NONE, 1, 1, 0};
            gemm_jobs<<<dim3(32, 8, 1), 256, 0, stream>>>(J, lambda_, td_miu, xb16, dx16, xx5, cOff);
        }
    }
}

// Round 9
// 1223.977 us; speedup vs baseline: 1.1114x; 1.1114x over previous
//
#include <hip/hip_runtime.h>
#include <hip/hip_bf16.h>
#include <cstdint>

typedef __bf16 bf16_t;
typedef __bf16 bf16x8 __attribute__((ext_vector_type(8)));
typedef float f32x4 __attribute__((ext_vector_type(4)));

#define BB 8
#define TT 2048
#define TC 512             // outer chunk length (4 chunks)
#define TCLOG 9
#define NCHUNK 4
#define MCH (BB*TC)        // 4096 local rows per chunk
#define CCH 1024
#define HH 16
#define HSZ 64
#define LR5 160            // 5 * LORA_R
#define LRP 192            // lora width padded to BKK multiple (cols 160..191 are zero)
#define TDR 64
#define TDK 128            // doubled K for hi/lo split w-GEMM
#define TSUB 64            // scan sub-chunk length
#define NSC (TC/TSUB)      // 8 sub-chunks per outer chunk
#define BBHH (BB*HH)       // 128
#define LDP 72             // LDS tile pitch for wkv tiles (64 + 8)

#define BM 128
#define BN 128
#define BKK 64             // R7 lesson: BKK=32 regressed (per-step overhead); 64 is optimal here

enum { EPI_NONE = 0, EPI_SILU = 1, EPI_TANH = 2, EPI_XX = 3, EPI_WBIAS = 4 };

// ---------------- async global->LDS, 16B per lane (m97 recipe) ----------------
__device__ __forceinline__ void gload16(const bf16_t* g, bf16_t* l) {
    __builtin_amdgcn_global_load_lds(
        (__attribute__((address_space(1))) void*)(g),
        (__attribute__((address_space(3))) void*)(l), 16, 0, 0);
}

// ---------------- f32 -> bf16 convert ----------------
__global__ __launch_bounds__(256) void f2b_kernel(const float* __restrict__ in,
        bf16_t* __restrict__ out, int n) {
    int i = blockIdx.x * 256 + threadIdx.x;
    if (i < n) out[i] = (bf16_t)in[i];
}

// ---------------- padded transpose+convert: in (R,Cc) f32 -> out (Cp,R) bf16, rows>=Cc zero ----------------
__global__ __launch_bounds__(256) void transb_pad(const float* __restrict__ in,
        bf16_t* __restrict__ out, int R, int Cc, int Cp) {
    int i = blockIdx.x * 256 + threadIdx.x;     // over Cp*R
    if (i >= Cp * R) return;
    int row = i / R, col = i - row * R;          // out[row][col]
    out[i] = (row < Cc) ? (bf16_t)in[(size_t)col * Cc + row] : (bf16_t)0.f;
}

// ---------------- block-diagonal B_lora -> Bbig [5120][192] bf16 (zeros included) ----------------
__global__ __launch_bounds__(256) void bbig_pad(const float* __restrict__ B_lora,
        bf16_t* __restrict__ Bbig) {
    int i = blockIdx.x * 256 + threadIdx.x;     // over 5*CCH*LRP
    if (i >= 5 * CCH * LRP) return;
    int row = i / LRP, col = i - row * LRP;
    int f = row >> 10, c = row & (CCH - 1);
    int lo = f * 32;
    float v = 0.f;
    if (col >= lo && col < lo + 32)
        v = B_lora[(size_t)(lo + (col - lo)) * CCH + c];
    Bbig[i] = (bf16_t)v;
}

// ---------------- td_B hi/lo split, transposed: (64,1024) f32 -> (1024,128) bf16 ----------------
__global__ __launch_bounds__(256) void tdb2_kernel(const float* __restrict__ td_B,
        bf16_t* __restrict__ tdB2) {
    int i = blockIdx.x * 256 + threadIdx.x;     // over CCH*TDR
    if (i >= CCH * TDR) return;
    int n = i >> 6, k = i & 63;
    float f = td_B[(size_t)k * CCH + n];
    bf16_t hi = (bf16_t)f;
    bf16_t lo = (bf16_t)(f - (float)hi);
    tdB2[(size_t)n * TDK + k] = hi;
    tdB2[(size_t)n * TDK + TDR + k] = lo;
}

// ---------------- xm + bf16 x / dxa chunk buffers (f32 in, bf16 out x3) ----------------
__global__ __launch_bounds__(256) void xm_kernel(const float* __restrict__ x,
        const float* __restrict__ miu_x, bf16_t* __restrict__ xm,
        bf16_t* __restrict__ xb, bf16_t* __restrict__ dxb, int cOff) {
    long long i = (long long)blockIdx.x * 256 + threadIdx.x;   // over MCH*CCH
    int ch = (int)(i & (CCH - 1));
    int btl = (int)(i >> 10);                 // local row in [0, MCH)
    int b = btl >> TCLOG, tau = btl & (TC - 1);
    int t = cOff + tau;
    size_t gi = ((size_t)b * TT + t) * CCH + ch;
    float xv = x[gi];
    float xp = (t > 0) ? x[gi - CCH] : 0.f;
    float dx = xp - xv;
    xm[i]  = (bf16_t)(xv + dx * miu_x[ch]);
    xb[i]  = (bf16_t)xv;
    dxb[i] = (bf16_t)dx;
}

// ---------------- job-batched MFMA GEMM: out[m,n] = sum_k A[m,k]*Bw[n,k] ----------------
// R6 configuration (best measured: 90us proj, conflicts=0):
// BKK=64 double-buffer + counted vmcnt(8) pipeline (next tile's 8 loads stay in
// flight across the barrier; drain to 0 only on last step) + T2 XOR swizzle
// (both-sides involution: source col ^= (row&7)<<3, read col ^= (row&7)<<3,
// LDS linear for gload_lds) + T5 setprio around MFMA cluster.
// Barrier 1: own old-8 done (vmcnt) for every wave => buf[cur] valid.
// Barrier 2: all reads done before any wave ISSUES next writes.
struct GJob {
    const bf16_t* A;     // [M=4096][K]
    const bf16_t* Bw;    // [nbmax][K], rows >= N are ZERO (padded)
    void* C;
    int N;               // valid output cols
    int nbmax;           // allocated B rows (block skipped if n0 >= nbmax)
    int K;
    int ldc;
    int epi;
    int outf32;
    int cmap;            // map m -> global token rows (cOff)
    int dup;             // duplicate store at n+64 (bf16 path only)
};
struct GJobs { GJob j[5]; };

__global__ __launch_bounds__(256) void gemm_jobs(GJobs jobs,
        const float* __restrict__ lam, const float* __restrict__ tdmiu,
        const bf16_t* __restrict__ xb, const bf16_t* __restrict__ dxb,
        bf16_t* __restrict__ xx5, int cOff) {
    const GJob jb = jobs.j[blockIdx.z];
    const int m0 = blockIdx.x * BM;
    const int n0 = blockIdx.y * BN;
    if (n0 >= jb.nbmax) return;              // block-uniform: no barrier divergence
    const int K = jb.K;
    __shared__ __align__(16) bf16_t As[2][BM * BKK];
    __shared__ __align__(16) bf16_t Bs[2][BN * BKK];
    const int tid = threadIdx.x;
    const int w = tid >> 6, lane = tid & 63;
    const int wm = (w >> 1) * 64, wn = (w & 1) * 64;  // 2x2 waves, 64x64 each
    const int lrow = lane & 15;
    const int kq = (lane >> 4) * 8;
    const int srow = tid >> 3;          // staging row base (0..31); row = srow + p*32
    // T2 source swizzle: (row&7) == (srow&7) since p*32 % 8 == 0 -> thread-const
    const int sc8 = ((tid & 7) * 8) ^ ((srow & 7) << 3);
    // T2 read swizzle: (row&7) == (lrow&7) since wm,16*mt % 8 == 0 -> thread-const
    const int rsw = (lrow & 7) << 3;
    const bf16_t* Ab = jb.A + (size_t)m0 * K;
    const bf16_t* Bb = jb.Bw + (size_t)n0 * K;
    f32x4 acc[4][4] = {};
    const int nsteps = K / BKK;

    auto stage = [&](int buf, int k0) {      // 8 vmem ops per thread
        #pragma unroll
        for (int p = 0; p < 4; ++p) {
            int r = srow + p * 32;
            // LDS dest (tid + p*256)*16B = wave-base + lane*16 (linear, m104-safe)
            gload16(Ab + (size_t)r * K + k0 + sc8, &As[buf][(tid + p * 256) * 8]);
            gload16(Bb + (size_t)r * K + k0 + sc8, &Bs[buf][(tid + p * 256) * 8]);
        }
    };

    stage(0, 0);
    int cur = 0;
    for (int s = 0; s < nsteps; ++s) {
        if (s + 1 < nsteps) {
            stage(cur ^ 1, (s + 1) * BKK);   // issue next tile: flies through barrier
            asm volatile("s_waitcnt vmcnt(8)" ::: "memory");   // old 8 (cur tile) done
        } else {
            asm volatile("s_waitcnt vmcnt(0)" ::: "memory");   // epilogue drain
        }
        __builtin_amdgcn_sched_barrier(0);
        __builtin_amdgcn_s_barrier();        // all waves' cur-tile loads landed
        __builtin_amdgcn_sched_barrier(0);
        __builtin_amdgcn_s_setprio(1);
        #pragma unroll
        for (int kk = 0; kk < BKK; kk += 32) {
            bf16x8 af[4], bfr[4];
            #pragma unroll
            for (int mt = 0; mt < 4; ++mt)
                af[mt] = *(const bf16x8*)(&As[cur][(wm + mt * 16 + lrow) * BKK + ((kk + kq) ^ rsw)]);
            #pragma unroll
            for (int nt = 0; nt < 4; ++nt)
                bfr[nt] = *(const bf16x8*)(&Bs[cur][(wn + nt * 16 + lrow) * BKK + ((kk + kq) ^ rsw)]);
            #pragma unroll
            for (int mt = 0; mt < 4; ++mt)
                #pragma unroll
                for (int nt = 0; nt < 4; ++nt)
                    acc[mt][nt] = __builtin_amdgcn_mfma_f32_16x16x32_bf16(
                        af[mt], bfr[nt], acc[mt][nt], 0, 0, 0);
        }
        __builtin_amdgcn_s_setprio(0);
        __builtin_amdgcn_sched_barrier(0);
        __builtin_amdgcn_s_barrier();        // reads done before next writes ISSUE
        cur ^= 1;
    }
    // C/D layout: col = lane&15, row = (lane>>4)*4 + reg  [verified m89/m91]
    const int rbase = (lane >> 4) * 4;
    const int col = lane & 15;
    if (jb.epi == EPI_XX) {
        #pragma unroll
        for (int mt = 0; mt < 4; ++mt)
            #pragma unroll
            for (int nt = 0; nt < 4; ++nt) {
                int n = n0 + wn + nt * 16 + col;
                int f = n >> 10, cch = n & (CCH - 1);
                #pragma unroll
                for (int rg = 0; rg < 4; ++rg) {
                    int m = m0 + wm + mt * 16 + rbase + rg;
                    size_t li = (size_t)m * CCH + cch;
                    float xv = (float)xb[li];
                    float dx = (float)dxb[li];
                    float miu = lam[f * CCH + cch] + acc[mt][nt][rg];
                    xx5[(size_t)(f * MCH + m) * CCH + cch] = (bf16_t)(xv + dx * miu);
                }
            }
        return;
    }
    #pragma unroll
    for (int mt = 0; mt < 4; ++mt) {
        #pragma unroll
        for (int nt = 0; nt < 4; ++nt) {
            int n = n0 + wn + nt * 16 + col;
            if (n >= jb.N) continue;
            #pragma unroll
            for (int rg = 0; rg < 4; ++rg) {
                int m = m0 + wm + mt * 16 + rbase + rg;
                size_t mg = jb.cmap ? ((size_t)(m >> TCLOG) * TT + cOff + (m & (TC - 1)))
                                    : (size_t)m;
                float vv = acc[mt][nt][rg];
                if (jb.epi == EPI_SILU) vv = vv / (1.f + expf(-vv));
                else if (jb.epi == EPI_TANH) vv = tanhf(vv);
                else if (jb.epi == EPI_WBIAS) vv += tdmiu[n];
                if (jb.outf32) {
                    ((float*)jb.C)[mg * jb.ldc + n] = vv;
                } else {
                    bf16_t hv = (bf16_t)vv;
                    ((bf16_t*)jb.C)[mg * jb.ldc + n] = hv;
                    if (jb.dup) ((bf16_t*)jb.C)[mg * jb.ldc + n + TDR] = hv;
                }
            }
        }
    }
}

// ---------------- WKV6 pass 1+2a fused: decay cumprods, operand tiles, Sloc GEMM ----------------
__global__ __launch_bounds__(64) void wkv_prepsg(const bf16_t* __restrict__ ry,
        const bf16_t* __restrict__ k, const float* __restrict__ w,
        const bf16_t* __restrict__ v, const float* __restrict__ u,
        bf16_t* __restrict__ rrT, bf16_t* __restrict__ ktT,
        float* __restrict__ PL, float* __restrict__ bvec,
        float* __restrict__ Sloc) {
    const int bh = blockIdx.x, sc = blockIdx.y;
    const int b = bh >> 4, h = bh & 15;
    const int j = threadIdx.x;
    const size_t base = ((size_t)b * TC + sc * TSUB) * CCH + h * HSZ + j;
    const size_t tile = ((size_t)bh * NSC + sc) * (TSUB * HSZ);
    const size_t vb = (size_t)bh * NSC + sc;
    __shared__ __align__(16) bf16_t ksT[HSZ * LDP];   // [i][s] = kt[s][i] (unscaled)
    __shared__ __align__(16) bf16_t vtT[HSZ * LDP];   // [n][s] = v[s][n]
    __shared__ float pls[HSZ];
    const float uj = u[h * HSZ + j];
    float pex = 1.f;
    for (int t = 0; t < TSUB; ++t) {
        size_t idx = base + (size_t)t * CCH;
        float rv = (float)ry[idx], kv = (float)k[idx], wv = w[idx];
        bf16_t vv = v[idx];
        float d = expf(-expf(wv));
        rrT[tile + t * HSZ + j] = (bf16_t)(rv * pex);
        float pinc = pex * d;
        bf16_t ktv = (bf16_t)(kv / pinc);   // |kt| <= ~3e11, bf16-safe
        ktT[tile + t * HSZ + j] = ktv;
        ksT[j * LDP + t] = ktv;
        vtT[j * LDP + t] = vv;
        float bu = rv * uj * kv;
        #pragma unroll
        for (int off = 1; off < 64; off <<= 1) bu += __shfl_xor(bu, off);
        if (j == 0) bvec[vb * TSUB + t] = bu;
        pex = pinc;
    }
    PL[vb * HSZ + j] = pex;
    pls[j] = pex;
    __syncthreads();
    // Sloc[i][n] = PL[i] * sum_s kt[s][i] * v[s][n]  (PL scale in f32 epilogue)
    const int lrow = j & 15, kq = (j >> 4) * 8;
    f32x4 acc[4][4] = {};
    #pragma unroll
    for (int kk = 0; kk < TSUB; kk += 32) {
        bf16x8 af[4], bfr[4];
        #pragma unroll
        for (int mt = 0; mt < 4; ++mt)
            af[mt] = *(const bf16x8*)(&ksT[(mt * 16 + lrow) * LDP + kk + kq]);
        #pragma unroll
        for (int nt = 0; nt < 4; ++nt)
            bfr[nt] = *(const bf16x8*)(&vtT[(nt * 16 + lrow) * LDP + kk + kq]);
        #pragma unroll
        for (int mt = 0; mt < 4; ++mt)
            #pragma unroll
            for (int nt = 0; nt < 4; ++nt)
                acc[mt][nt] = __builtin_amdgcn_mfma_f32_16x16x32_bf16(
                    af[mt], bfr[nt], acc[mt][nt], 0, 0, 0);
    }
    const int rbase = (j >> 4) * 4, col = j & 15;
    #pragma unroll
    for (int mt = 0; mt < 4; ++mt)
        #pragma unroll
        for (int nt = 0; nt < 4; ++nt)
            #pragma unroll
            for (int rg = 0; rg < 4; ++rg) {
                int i = mt * 16 + rbase + rg, n = nt * 16 + col;
                Sloc[tile + i * HSZ + n] = pls[i] * acc[mt][nt][rg];
            }
}

// ---------------- WKV6 pass 2b: serial state combine, 4x parallel over i-groups ----------------
// 256 threads: thread = (ig, j); each owns 16 state rows. Arithmetic order per
// element identical to the 64-thread version (bit-exact); 4x fewer serial iters.
__global__ __launch_bounds__(256) void wkv_combine(const float* __restrict__ Sloc,
        const float* __restrict__ PL, float* __restrict__ S0st,
        float* state, int cOuter) {
    const int bh = blockIdx.x;
    const int j = threadIdx.x & 63;
    const int ig = threadIdx.x >> 6;          // 0..3 -> rows ig*16 .. ig*16+15
    float* st = state + (size_t)bh * HSZ * HSZ;
    float S[16];
    if (cOuter > 0) {
        #pragma unroll
        for (int ii = 0; ii < 16; ++ii) S[ii] = st[(ig * 16 + ii) * HSZ + j];
    } else {
        #pragma unroll
        for (int ii = 0; ii < 16; ++ii) S[ii] = 0.f;
    }
    __shared__ float pls[HSZ];
    for (int sc = 0; sc < NSC; ++sc) {
        const size_t so = ((size_t)bh * NSC + sc) * (HSZ * HSZ);
        if (threadIdx.x < HSZ)
            pls[threadIdx.x] = PL[((size_t)bh * NSC + sc) * HSZ + threadIdx.x];
        __syncthreads();
        #pragma unroll
        for (int ii = 0; ii < 16; ++ii) {
            int i = ig * 16 + ii;
            S0st[so + i * HSZ + j] = S[ii];
            S[ii] = pls[i] * S[ii] + Sloc[so + i * HSZ + j];
        }
        __syncthreads();
    }
    #pragma unroll
    for (int ii = 0; ii < 16; ++ii) st[(ig * 16 + ii) * HSZ + j] = S[ii];
}

// ---------------- WKV6 pass 3: Y = (mask(RR@KTt) + diag(b)) @ V + RR @ S0 ----------------
__global__ __launch_bounds__(64) void wkv_y(bf16_t* __restrict__ ry,
        const bf16_t* __restrict__ rrT, const bf16_t* __restrict__ ktT,
        const bf16_t* __restrict__ v, const float* __restrict__ S0st,
        const float* __restrict__ bvec) {
    const int bh = blockIdx.x, sc = blockIdx.y;
    const int b = bh >> 4, h = bh & 15;
    const int j = threadIdx.x;
    const size_t tile = ((size_t)bh * NSC + sc) * (TSUB * HSZ);
    const size_t basev = ((size_t)b * TC + sc * TSUB) * CCH + h * HSZ;
    __shared__ __align__(16) bf16_t vtT[HSZ * LDP];   // [j][s] = v[s][j]
    __shared__ __align__(16) bf16_t s0T[HSZ * LDP];   // [j][i] = S0[i][j]
    __shared__ __align__(16) bf16_t am[TSUB * LDP];   // masked A [t][s]
    __shared__ float bl[TSUB];
    for (int s = 0; s < TSUB; ++s)
        vtT[j * LDP + s] = v[basev + (size_t)s * CCH + j];
    for (int i = 0; i < HSZ; ++i)
        s0T[j * LDP + i] = (bf16_t)S0st[tile + i * HSZ + j];
    bl[j] = bvec[((size_t)bh * NSC + sc) * TSUB + j];
    __syncthreads();
    const bf16_t* rrt = rrT + tile;
    const bf16_t* ktt = ktT + tile;
    const int lane = j;
    const int lrow = lane & 15, kq = (lane >> 4) * 8;
    const int rbase = (lane >> 4) * 4, col = lane & 15;
    // phase 1: A = RR @ KTt^T  (K = channel)
    f32x4 acc[4][4] = {};
    #pragma unroll
    for (int kk = 0; kk < HSZ; kk += 32) {
        bf16x8 af[4], bfr[4];
        #pragma unroll
        for (int mt = 0; mt < 4; ++mt)
            af[mt] = *(const bf16x8*)(rrt + (mt * 16 + lrow) * HSZ + kk + kq);
        #pragma unroll
        for (int nt = 0; nt < 4; ++nt)
            bfr[nt] = *(const bf16x8*)(ktt + (nt * 16 + lrow) * HSZ + kk + kq);
        #pragma unroll
        for (int mt = 0; mt < 4; ++mt)
            #pragma unroll
            for (int nt = 0; nt < 4; ++nt)
                acc[mt][nt] = __builtin_amdgcn_mfma_f32_16x16x32_bf16(
                    af[mt], bfr[nt], acc[mt][nt], 0, 0, 0);
    }
    // mask strict-lower, diag = b_t, upper = 0
    #pragma unroll
    for (int mt = 0; mt < 4; ++mt)
        #pragma unroll
        for (int nt = 0; nt < 4; ++nt)
            #pragma unroll
            for (int rg = 0; rg < 4; ++rg) {
                int t = mt * 16 + rbase + rg, s = nt * 16 + col;
                float aval = (s < t) ? acc[mt][nt][rg] : ((s == t) ? bl[t] : 0.f);
                am[t * LDP + s] = (bf16_t)aval;
            }
    __syncthreads();
    // phase 2: Y = A @ V  (K = s)  +  RR @ S0 (K = i)
    f32x4 yac[4][4] = {};
    #pragma unroll
    for (int kk = 0; kk < TSUB; kk += 32) {
        bf16x8 af[4], bfr[4];
        #pragma unroll
        for (int mt = 0; mt < 4; ++mt)
            af[mt] = *(const bf16x8*)(&am[(mt * 16 + lrow) * LDP + kk + kq]);
        #pragma unroll
        for (int nt = 0; nt < 4; ++nt)
            bfr[nt] = *(const bf16x8*)(&vtT[(nt * 16 + lrow) * LDP + kk + kq]);
        #pragma unroll
        for (int mt = 0; mt < 4; ++mt)
            #pragma unroll
            for (int nt = 0; nt < 4; ++nt)
                yac[mt][nt] = __builtin_amdgcn_mfma_f32_16x16x32_bf16(
                    af[mt], bfr[nt], yac[mt][nt], 0, 0, 0);
    }
    #pragma unroll
    for (int kk = 0; kk < HSZ; kk += 32) {
        bf16x8 af[4], bfr[4];
        #pragma unroll
        for (int mt = 0; mt < 4; ++mt)
            af[mt] = *(const bf16x8*)(rrt + (mt * 16 + lrow) * HSZ + kk + kq);
        #pragma unroll
        for (int nt = 0; nt < 4; ++nt)
            bfr[nt] = *(const bf16x8*)(&s0T[(nt * 16 + lrow) * LDP + kk + kq]);
        #pragma unroll
        for (int mt = 0; mt < 4; ++mt)
            #pragma unroll
            for (int nt = 0; nt < 4; ++nt)
                yac[mt][nt] = __builtin_amdgcn_mfma_f32_16x16x32_bf16(
                    af[mt], bfr[nt], yac[mt][nt], 0, 0, 0);
    }
    #pragma unroll
    for (int mt = 0; mt < 4; ++mt)
        #pragma unroll
        for (int nt = 0; nt < 4; ++nt)
            #pragma unroll
            for (int rg = 0; rg < 4; ++rg) {
                int t = mt * 16 + rbase + rg, jc = nt * 16 + col;
                ry[basev + (size_t)t * CCH + jc] = (bf16_t)yac[mt][nt][rg];
            }
}

// ---------------- GroupNorm(16 groups of 64) * g, in-place on y chunk ----------------
__global__ __launch_bounds__(256) void gn_kernel(bf16_t* yg,
        const float* __restrict__ g_glob, const float* __restrict__ gamma,
        const float* __restrict__ beta, int cOff) {
    int wave = threadIdx.x >> 6, lane = threadIdx.x & 63;
    int gid = blockIdx.x * 4 + wave;          // over MCH*HH
    int h = gid & (HH - 1);
    int ml = gid >> 4;                        // local token row
    int b = ml >> TCLOG, tau = ml & (TC - 1);
    size_t lidx = (size_t)ml * CCH + h * HSZ + lane;
    size_t gidx = ((size_t)b * TT + cOff + tau) * CCH + h * HSZ + lane;
    float val = (float)yg[lidx];
    float s = val, s2 = val * val;
    #pragma unroll
    for (int off = 32; off > 0; off >>= 1) {
        s  += __shfl_xor(s, off);
        s2 += __shfl_xor(s2, off);
    }
    float mean = s * (1.f / HSZ);
    float var  = fmaxf(s2 * (1.f / HSZ) - mean * mean, 0.f);
    float inv  = rsqrtf(var + 1e-5f * HH);
    float yn = (val - mean) * inv * gamma[h * HSZ + lane] + beta[h * HSZ + lane];
    yg[lidx] = (bf16_t)(yn * g_glob[gidx]);
}

extern "C" void kernel_launch(void* const* d_in, const int* in_sizes, int n_in,
                              void* d_out, int out_size, void* d_ws, size_t ws_size,
                              hipStream_t stream) {
    const float* x       = (const float*)d_in[0];
    const float* miu_x   = (const float*)d_in[1];
    const float* lambda_ = (const float*)d_in[2];
    const float* A_lora  = (const float*)d_in[3];
    const float* B_lora  = (const float*)d_in[4];
    const float* td_miu  = (const float*)d_in[5];
    const float* td_A    = (const float*)d_in[6];
    const float* td_B    = (const float*)d_in[7];
    const float* u       = (const float*)d_in[8];
    const float* Wr      = (const float*)d_in[9];
    const float* Wk      = (const float*)d_in[10];
    const float* Wv      = (const float*)d_in[11];
    const float* Wg      = (const float*)d_in[12];
    const float* Wo      = (const float*)d_in[13];
    const float* gamma   = (const float*)d_in[14];
    const float* beta    = (const float*)d_in[15];
    float* out = (float*)d_out;

    // ---- workspace carve-up (~114 MiB) ----
    char* ws = (char*)d_ws;
    size_t off = 0;
    auto alloc = [&](size_t bytes) {
        char* p = ws + off;
        off += (bytes + 255) & ~(size_t)255;
        return (void*)p;
    };
    const size_t MCC = (size_t)MCH * CCH;               // 4M elems per chunk buffer
    // Aliasing plan (all lifetimes disjoint within the serial per-chunk schedule):
    //   xm  -> xx5+4MCC   (dead after lora GEMM)
    //   Sloc-> xx5[0..2)  S0st -> xx5[2..4)   (written after xx consumed)
    //   xb  -> kc,  dxb -> vc   (dead after EPI_XX; kc/vc written by projections after)
    bf16_t* xx5  = (bf16_t*)alloc(5 * MCC * 2);         // 40 MB
    float*  Sloc = (float*)xx5;                          // 16 MB over xx0,xx1
    float*  S0st = (float*)(xx5 + 2 * MCC);              // 16 MB over xx2,xx3
    bf16_t* xmb  = xx5 + 4 * MCC;                        //  8 MB over xx4
    bf16_t* kc   = (bf16_t*)alloc(MCC * 2);
    bf16_t* vc   = (bf16_t*)alloc(MCC * 2);
    bf16_t* xb16 = kc;                                   // bf16 x chunk (pre-projection)
    bf16_t* dx16 = vc;                                   // bf16 dxa chunk
    float*  wc   = (float*)alloc(MCC * 4);              // f32 w (fed to exp cumprod)
    bf16_t* ryc  = (bf16_t*)alloc(MCC * 2);             // r -> y -> yn*g
    bf16_t* rrT  = (bf16_t*)alloc(MCC * 2);
    bf16_t* ktT  = (bf16_t*)alloc(MCC * 2);
    bf16_t* lhcp = (bf16_t*)alloc((size_t)MCH * LRP * 2);   // tanh lora hidden, padded
    bf16_t* tdh2 = (bf16_t*)alloc((size_t)MCH * TDK * 2);   // tanh td hidden, duplicated cols
    bf16_t* At   = (bf16_t*)alloc((size_t)256 * CCH * 2);   // lora A^T, rows 160.. zero
    bf16_t* tdAt = (bf16_t*)alloc((size_t)128 * CCH * 2);   // td A^T, rows 64.. zero
    bf16_t* tdB2 = (bf16_t*)alloc((size_t)CCH * TDK * 2);   // td_B^T hi|lo split
    bf16_t* Bbig = (bf16_t*)alloc((size_t)5 * CCH * LRP * 2); // block-diag B_lora
    bf16_t* Wb[5];
    for (int i = 0; i < 5; ++i) Wb[i] = (bf16_t*)alloc((size_t)CCH * CCH * 2);
    float*  state = (float*)alloc((size_t)BBHH * HSZ * HSZ * 4);
    float*  PL    = (float*)alloc((size_t)BBHH * NSC * HSZ * 4);
    float*  bvec  = (float*)alloc((size_t)BBHH * NSC * TSUB * 4);
    (void)ws_size; (void)in_sizes; (void)n_in; (void)out_size;
    bf16_t* Wrb = Wb[0]; bf16_t* Wkb = Wb[1]; bf16_t* Wvb = Wb[2];
    bf16_t* Wgb = Wb[3]; bf16_t* Wob = Wb[4];

    // ---- weight prep (kernels only; no runtime memset -> graph-capture safe) ----
    const int WN = CCH * CCH;
    f2b_kernel<<<(WN + 255) / 256, 256, 0, stream>>>(Wr, Wrb, WN);
    f2b_kernel<<<(WN + 255) / 256, 256, 0, stream>>>(Wk, Wkb, WN);
    f2b_kernel<<<(WN + 255) / 256, 256, 0, stream>>>(Wv, Wvb, WN);
    f2b_kernel<<<(WN + 255) / 256, 256, 0, stream>>>(Wg, Wgb, WN);
    f2b_kernel<<<(WN + 255) / 256, 256, 0, stream>>>(Wo, Wob, WN);
    transb_pad<<<(256 * CCH + 255) / 256, 256, 0, stream>>>(A_lora, At, CCH, LR5, 256);
    transb_pad<<<(128 * CCH + 255) / 256, 256, 0, stream>>>(td_A, tdAt, CCH, TDR, 128);
    tdb2_kernel<<<(CCH * TDR + 255) / 256, 256, 0, stream>>>(td_B, tdB2);
    bbig_pad<<<(5 * CCH * LRP + 255) / 256, 256, 0, stream>>>(B_lora, Bbig);

    for (int c = 0; c < NCHUNK; ++c) {
        const int cOff = c * TC;
        // xm + bf16 x/dxa chunk buffers (xb16/dx16 live until EPI_XX completes)
        xm_kernel<<<MCC / 256, 256, 0, stream>>>(x, miu_x, xmb, xb16, dx16, cOff);
        // lora hidden: lhcp = tanh(xm @ A_lora), cols 160..191 = tanh(0) = 0
        {
            GJobs J = {};
            J.j[0] = {xmb, At, lhcp, LRP, 256, CCH, LRP, EPI_TANH, 0, 0, 0};
            gemm_jobs<<<dim3(32, 2, 1), 256, 0, stream>>>(J, lambda_, td_miu, xb16, dx16, xx5, cOff);
        }
        // miu GEMM + ddlerp epilogue -> all 5 xx branch buffers
        {
            GJobs J = {};
            J.j[0] = {lhcp, Bbig, nullptr, 5 * CCH, 5 * CCH, LRP, 0, EPI_XX, 0, 0, 0};
            gemm_jobs<<<dim3(32, 40, 1), 256, 0, stream>>>(J, lambda_, td_miu, xb16, dx16, xx5, cOff);
        }
        // batched projections: k, v, r, g(silu->out f32), td hidden(tanh, dup cols)
        {
            GJobs J = {};
            J.j[0] = {xx5 + 1 * MCC, Wkb,  kc,   CCH, CCH, CCH, CCH, EPI_NONE, 0, 0, 0};
            J.j[1] = {xx5 + 2 * MCC, Wvb,  vc,   CCH, CCH, CCH, CCH, EPI_NONE, 0, 0, 0};
            J.j[2] = {xx5 + 3 * MCC, Wrb,  ryc,  CCH, CCH, CCH, CCH, EPI_NONE, 0, 0, 0};
            J.j[3] = {xx5 + 4 * MCC, Wgb,  out,  CCH, CCH, CCH, CCH, EPI_SILU, 1, 1, 0};
            J.j[4] = {xx5 + 0 * MCC, tdAt, tdh2, TDR, 128, CCH, TDK, EPI_TANH, 0, 0, 1};
            gemm_jobs<<<dim3(32, 8, 5), 256, 0, stream>>>(J, lambda_, td_miu, xb16, dx16, xx5, cOff);
        }
        // w = td_miu + tdh2 @ [hi|lo]^T  (MFMA, f32-grade via hi/lo split, f32 out)
        {
            GJobs J = {};
            J.j[0] = {tdh2, tdB2, wc, CCH, CCH, TDK, CCH, EPI_WBIAS, 1, 0, 0};
            gemm_jobs<<<dim3(32, 8, 1), 256, 0, stream>>>(J, lambda_, td_miu, xb16, dx16, xx5, cOff);
        }
        // scan: fused prep+state-GEMM (writes Sloc over dead xx0/xx1) -> combine -> Y
        wkv_prepsg<<<dim3(BBHH, NSC), 64, 0, stream>>>(ryc, kc, wc, vc, u,
                                                       rrT, ktT, PL, bvec, Sloc);
        wkv_combine<<<BBHH, 256, 0, stream>>>(Sloc, PL, S0st, state, c);
        wkv_y<<<dim3(BBHH, NSC), 64, 0, stream>>>(ryc, rrT, ktT, vc, S0st, bvec);
        // groupnorm * g, then Wo projection (f32 out, global rows)
        gn_kernel<<<(MCH * HH) / 4, 256, 0, stream>>>(ryc, out, gamma, beta, cOff);
        {
            GJobs J = {};
            J.j[0] = {ryc, Wob, out, CCH, CCH, CCH, CCH, EPI_NONE, 1, 1, 0};
            gemm_jobs<<<dim3(32, 8, 1), 256, 0, stream>>>(J, lambda_, td_miu, xb16, dx16, xx5, cOff);
        }
    }
}